// Round 12
// baseline (414.080 us; speedup 1.0000x reference)
//
#include <hip/hip_runtime.h>
#include <hip/hip_bf16.h>
#include <math.h>

// Problem constants (fixed by the reference file)
#define T_TOK 2048
#define H_DIM 1024
#define I_DIM 2048
#define E_NUM 8
#define TOPK  2
#define P_MAX (T_TOK * TOPK)   // 4096 (token, k) pairs
#define MAX_SLOTS 40           // max 128-row slots: 4096/128 + 8

typedef __bf16 bf16_t;
typedef __attribute__((ext_vector_type(8))) __bf16 bf16x8;
typedef __attribute__((ext_vector_type(4))) float  f32x4;

// global_load_lds: per-lane GLOBAL address, wave-uniform LDS base; lane n
// writes lds_base + n*16 bytes (m104/m108).
#define GLOAD_LDS16(gptr, lptr)                                                   \
    __builtin_amdgcn_global_load_lds(                                             \
        (const __attribute__((address_space(1))) void*)(gptr),                    \
        (__attribute__((address_space(3))) void*)(lptr), 16, 0, 0)

__device__ inline f32x4 zero4() {
    f32x4 z; z[0] = 0.f; z[1] = 0.f; z[2] = 0.f; z[3] = 0.f; return z;
}

__device__ inline bf16x8 cvt8(f32x4 a, f32x4 b) {
    bf16x8 o;
    o[0] = (bf16_t)a[0]; o[1] = (bf16_t)a[1]; o[2] = (bf16_t)a[2]; o[3] = (bf16_t)a[3];
    o[4] = (bf16_t)b[0]; o[5] = (bf16_t)b[1]; o[6] = (bf16_t)b[2]; o[7] = (bf16_t)b[3];
    return o;
}

// ---------------------------------------------------------------- init
__global__ void init_kernel(int* counts, int* cursor) {
    int i = threadIdx.x;
    if (i < E_NUM) { counts[i] = 0; cursor[i] = 0; }
}

// ---------------------------------------------------------------- router
__global__ void router_kernel(const float* __restrict__ gating,
                              int* __restrict__ expert_id,
                              float* __restrict__ wt,
                              int* __restrict__ counts) {
    int t = blockIdx.x * blockDim.x + threadIdx.x;
    if (t >= T_TOK) return;
    float l[E_NUM];
    float m = -1e30f;
    #pragma unroll
    for (int e = 0; e < E_NUM; e++) { l[e] = gating[t * E_NUM + e]; m = fmaxf(m, l[e]); }
    float p[E_NUM];
    #pragma unroll
    for (int e = 0; e < E_NUM; e++) p[e] = __expf(l[e] - m);
    int i0 = 0; float p0 = p[0];
    #pragma unroll
    for (int e = 1; e < E_NUM; e++) if (p[e] > p0) { p0 = p[e]; i0 = e; }
    int i1 = -1; float p1 = -1.f;
    #pragma unroll
    for (int e = 0; e < E_NUM; e++) if (e != i0 && p[e] > p1) { p1 = p[e]; i1 = e; }
    float inv = 1.f / (p0 + p1);
    expert_id[t * 2 + 0] = i0; wt[t * 2 + 0] = p0 * inv;
    expert_id[t * 2 + 1] = i1; wt[t * 2 + 1] = p1 * inv;
    atomicAdd(&counts[i0], 1);
    atomicAdd(&counts[i1], 1);
}

// ---------------------------------------------------------------- scan + tile map
__global__ void scan_kernel(const int* __restrict__ counts,
                            int* __restrict__ offsets,
                            int* __restrict__ tile_e, int* __restrict__ tile_m0,
                            int* __restrict__ n_slots) {
    if (threadIdx.x != 0 || blockIdx.x != 0) return;
    int off = 0;
    for (int e = 0; e < E_NUM; e++) { offsets[e] = off; off += counts[e]; }
    offsets[E_NUM] = off;
    int s = 0;
    for (int e = 0; e < E_NUM; e++)
        for (int m0 = offsets[e]; m0 < offsets[e + 1]; m0 += 128) {
            tile_e[s] = e; tile_m0[s] = m0; s++;
        }
    *n_slots = s;
}

// ---------------------------------------------------------------- scatter
__global__ void scatter_kernel(const int* __restrict__ expert_id,
                               const float* __restrict__ wt,
                               const int* __restrict__ offsets,
                               int* __restrict__ cursor,
                               int* __restrict__ pair_token,
                               int* __restrict__ pair_dst,
                               float* __restrict__ pair_wt) {
    int t = blockIdx.x * blockDim.x + threadIdx.x;
    if (t >= T_TOK) return;
    #pragma unroll
    for (int k = 0; k < TOPK; k++) {
        int e = expert_id[t * 2 + k];
        int p = offsets[e] + atomicAdd(&cursor[e], 1);
        pair_token[p] = t;
        pair_dst[p]   = t * 2 + k;
        pair_wt[p]    = wt[t * 2 + k];
    }
}

// ---------------------------------------------------------------- f32 -> bf16 convert
__global__ void convert_kernel(const float* __restrict__ src,
                               bf16_t* __restrict__ dst) {
    size_t base = ((size_t)blockIdx.x * blockDim.x + threadIdx.x) * 16;
    f32x4 v0 = *(const f32x4*)(src + base);
    f32x4 v1 = *(const f32x4*)(src + base + 4);
    f32x4 v2 = *(const f32x4*)(src + base + 8);
    f32x4 v3 = *(const f32x4*)(src + base + 12);
    *(bf16x8*)(dst + base)     = cvt8(v0, v1);
    *(bf16x8*)(dst + base + 8) = cvt8(v2, v3);
}

// ---------------------------------------------------------------- GEMM1 + SwiGLU
// R8 counted-vmcnt pipeline (T3/T4), UNCHANGED engine. One fix: R8's grid
// of 512 < nit (~528) made ~16 blocks run 2 sequential items -> wall =
// 2 x T_item with the GPU ~idle in gen 2 (Occupancy 26.5% confirmed this).
// Now: grid 768 = 3 blocks/CU (LDS 48KB x 3 = 144 <= 160KB; VGPR 60 <= 84)
// via __launch_bounds__(512, 6) -> ALL items resident in one generation.
__global__ __launch_bounds__(512, 6)
void gemm1_kernel(const bf16_t* __restrict__ hbf,
                  const bf16_t* __restrict__ w1bf,
                  const int* __restrict__ pair_token,
                  const int* __restrict__ offsets,
                  const int* __restrict__ tile_e,
                  const int* __restrict__ tile_m0,
                  const int* __restrict__ n_slots,
                  bf16_t* __restrict__ act) {
    __shared__ __align__(16) bf16_t sA[2][128][32];  // 16 KB
    __shared__ __align__(16) bf16_t sB[2][256][32];  // 32 KB

    int tid = threadIdx.x;
    int lane = tid & 63, w = tid >> 6;     // 8 waves
    int wm = w >> 2, wn = w & 3;           // 2M x 4N
    int l15 = lane & 15, lg = lane >> 4;
    int sr = lane >> 2, sg = lane & 3;     // staging sub-row / granule
    int gcol = (sg ^ (sr & 3)) * 8;        // inverse-swizzled SOURCE granule
    int rg   = (lg ^ (l15 & 3)) * 8;       // swizzled READ granule

    int nit = *n_slots * 16;
    for (int it = blockIdx.x; it < nit; it += gridDim.x) {
        int slot = it >> 4;
        int c0   = (it & 15) << 7;         // act cols [c0, c0+128)
        int e    = tile_e[slot];
        int m0   = tile_m0[slot];
        int mend = offsets[e + 1];
        const bf16_t* w1e = w1bf + (size_t)e * (2 * I_DIM) * H_DIM;

        // staging addresses (k0 added in loop)
        int parow = m0 + w * 16 + sr;
        int tok = (parow < mend) ? pair_token[parow] : 0;  // dummy, masked later
        const bf16_t* gA0 = hbf + (size_t)tok * H_DIM + gcol;
        int br0 = w * 32 + sr, br1 = br0 + 16;
        int wr0 = (br0 < 128) ? (c0 + br0) : (I_DIM + c0 + br0 - 128);
        int wr1 = (br1 < 128) ? (c0 + br1) : (I_DIM + c0 + br1 - 128);
        const bf16_t* gB0 = w1e + (size_t)wr0 * H_DIM + gcol;
        const bf16_t* gB1 = w1e + (size_t)wr1 * H_DIM + gcol;

        f32x4 acc[4][4];  // j=0,1 gate; j=2,3 up
        #pragma unroll
        for (int i = 0; i < 4; i++)
            #pragma unroll
            for (int j = 0; j < 4; j++) acc[i][j] = zero4();

        // prologue: stage K-step 0 into buf 0
        GLOAD_LDS16(gA0, &sA[0][w * 16][0]);
        GLOAD_LDS16(gB0, &sB[0][w * 32][0]);
        GLOAD_LDS16(gB1, &sB[0][w * 32 + 16][0]);

        for (int t = 0; t < 32; t++) {
            int cur = t & 1;
            if (t < 31) {
                int k0 = (t + 1) * 32;
                GLOAD_LDS16(gA0 + k0, &sA[cur ^ 1][w * 16][0]);
                GLOAD_LDS16(gB0 + k0, &sB[cur ^ 1][w * 32][0]);
                GLOAD_LDS16(gB1 + k0, &sB[cur ^ 1][w * 32 + 16][0]);
                asm volatile("s_waitcnt vmcnt(3)" ::: "memory");
            } else {
                asm volatile("s_waitcnt vmcnt(0)" ::: "memory");
            }
            __builtin_amdgcn_s_barrier();   // all waves' cur-tile loads landed

            bf16x8 a[4], bg[2], bu[2];
            #pragma unroll
            for (int i = 0; i < 4; i++)
                a[i] = *(const bf16x8*)&sA[cur][wm * 64 + i * 16 + l15][rg];
            #pragma unroll
            for (int j = 0; j < 2; j++) {
                bg[j] = *(const bf16x8*)&sB[cur][wn * 32 + j * 16 + l15][rg];
                bu[j] = *(const bf16x8*)&sB[cur][128 + wn * 32 + j * 16 + l15][rg];
            }
            #pragma unroll
            for (int i = 0; i < 4; i++)
                #pragma unroll
                for (int j = 0; j < 2; j++) {
                    acc[i][j]     = __builtin_amdgcn_mfma_f32_16x16x32_bf16(a[i], bg[j], acc[i][j], 0, 0, 0);
                    acc[i][2 + j] = __builtin_amdgcn_mfma_f32_16x16x32_bf16(a[i], bu[j], acc[i][2 + j], 0, 0, 0);
                }
            __builtin_amdgcn_sched_barrier(0);  // keep MFMAs before barrier
            __builtin_amdgcn_s_barrier();       // cur reusable for next stage
        }

        // epilogue: act = silu(gate) * up
        #pragma unroll
        for (int i = 0; i < 4; i++) {
            #pragma unroll
            for (int rr = 0; rr < 4; rr++) {
                int m = m0 + wm * 64 + i * 16 + lg * 4 + rr;
                if (m < mend) {
                    #pragma unroll
                    for (int j = 0; j < 2; j++) {
                        float gv = acc[i][j][rr];
                        float uv = acc[i][2 + j][rr];
                        float sv = gv / (1.f + __expf(-gv));
                        act[(size_t)m * I_DIM + c0 + wn * 32 + j * 16 + l15] = (bf16_t)(sv * uv);
                    }
                }
            }
        }
    }
}

// ---------------------------------------------------------------- GEMM2 (+ scale, k-split)
// R8 engine unchanged. nit = n_slots*8 (~264) <= 512 block slots at
// 2 blocks/CU -> already fully resident; grid 512 covers worst case.
__global__ __launch_bounds__(512, 4)
void gemm2_kernel(const bf16_t* __restrict__ act,
                  const bf16_t* __restrict__ w2bf,
                  const int* __restrict__ offsets,
                  const int* __restrict__ tile_e,
                  const int* __restrict__ tile_m0,
                  const int* __restrict__ n_slots,
                  const int* __restrict__ pair_dst,
                  const float* __restrict__ pair_wt,
                  float* __restrict__ ybuf) {
    __shared__ __align__(16) bf16_t sA[2][128][32];
    __shared__ __align__(16) bf16_t sB[2][256][32];

    int tid = threadIdx.x;
    int lane = tid & 63, w = tid >> 6;
    int wm = w >> 2, wn = w & 3;
    int l15 = lane & 15, lg = lane >> 4;
    int sr = lane >> 2, sg = lane & 3;
    int gcol = (sg ^ (sr & 3)) * 8;
    int rg   = (lg ^ (l15 & 3)) * 8;

    int nit = *n_slots * 8;    // 4 n0-groups x 2 kz
    for (int it = blockIdx.x; it < nit; it += gridDim.x) {
        int slot = it >> 3;
        int n0   = ((it >> 1) & 3) << 8;   // out cols [n0, n0+256)
        int kz   = it & 1;
        int kb   = kz << 10;               // k-slice base (1024)
        int e    = tile_e[slot];
        int m0   = tile_m0[slot];
        int mend = offsets[e + 1];
        const bf16_t* w2e = w2bf + (size_t)e * H_DIM * I_DIM;

        // rows >= mend read neighbor arena data (masked at epilogue)
        const bf16_t* gA0 = act + (size_t)(m0 + w * 16 + sr) * I_DIM + kb + gcol;
        const bf16_t* gB0 = w2e + (size_t)(n0 + w * 32 + sr) * I_DIM + kb + gcol;
        const bf16_t* gB1 = w2e + (size_t)(n0 + w * 32 + 16 + sr) * I_DIM + kb + gcol;

        f32x4 acc[4][4];
        #pragma unroll
        for (int i = 0; i < 4; i++)
            #pragma unroll
            for (int j = 0; j < 4; j++) acc[i][j] = zero4();

        GLOAD_LDS16(gA0, &sA[0][w * 16][0]);
        GLOAD_LDS16(gB0, &sB[0][w * 32][0]);
        GLOAD_LDS16(gB1, &sB[0][w * 32 + 16][0]);

        for (int t = 0; t < 32; t++) {
            int cur = t & 1;
            if (t < 31) {
                int k0 = (t + 1) * 32;
                GLOAD_LDS16(gA0 + k0, &sA[cur ^ 1][w * 16][0]);
                GLOAD_LDS16(gB0 + k0, &sB[cur ^ 1][w * 32][0]);
                GLOAD_LDS16(gB1 + k0, &sB[cur ^ 1][w * 32 + 16][0]);
                asm volatile("s_waitcnt vmcnt(3)" ::: "memory");
            } else {
                asm volatile("s_waitcnt vmcnt(0)" ::: "memory");
            }
            __builtin_amdgcn_s_barrier();

            bf16x8 a[4], b[4];
            #pragma unroll
            for (int i = 0; i < 4; i++)
                a[i] = *(const bf16x8*)&sA[cur][wm * 64 + i * 16 + l15][rg];
            #pragma unroll
            for (int j = 0; j < 4; j++)
                b[j] = *(const bf16x8*)&sB[cur][wn * 64 + j * 16 + l15][rg];
            #pragma unroll
            for (int i = 0; i < 4; i++)
                #pragma unroll
                for (int j = 0; j < 4; j++)
                    acc[i][j] = __builtin_amdgcn_mfma_f32_16x16x32_bf16(a[i], b[j], acc[i][j], 0, 0, 0);
            __builtin_amdgcn_sched_barrier(0);
            __builtin_amdgcn_s_barrier();
        }

        float* ybufz = ybuf + (size_t)kz * P_MAX * H_DIM;
        #pragma unroll
        for (int i = 0; i < 4; i++) {
            #pragma unroll
            for (int rr = 0; rr < 4; rr++) {
                int m = m0 + wm * 64 + i * 16 + lg * 4 + rr;
                if (m < mend) {
                    int   dst = pair_dst[m];
                    float wv  = pair_wt[m];
                    #pragma unroll
                    for (int j = 0; j < 4; j++)
                        ybufz[(size_t)dst * H_DIM + n0 + wn * 64 + j * 16 + l15] = acc[i][j][rr] * wv;
                }
            }
        }
    }
}

// ---------------------------------------------------------------- combine
__global__ void combine_kernel(const float* __restrict__ ybuf,
                               float* __restrict__ out) {
    int idx = blockIdx.x * 256 + threadIdx.x;   // one float4 each
    int t = idx >> 8;                           // 256 float4 per token row
    int h = idx & 255;
    const size_t SL = (size_t)P_MAX * H_DIM;
    const f32x4* y00 = (const f32x4*)(ybuf + (size_t)(t * 2)     * H_DIM) + h;
    const f32x4* y01 = (const f32x4*)(ybuf + (size_t)(t * 2 + 1) * H_DIM) + h;
    const f32x4* y10 = (const f32x4*)(ybuf + SL + (size_t)(t * 2)     * H_DIM) + h;
    const f32x4* y11 = (const f32x4*)(ybuf + SL + (size_t)(t * 2 + 1) * H_DIM) + h;
    f32x4 s = (*y00 + *y10) + (*y01 + *y11);
    ((f32x4*)out)[idx] = s;
}

// ---------------------------------------------------------------- launch
extern "C" void kernel_launch(void* const* d_in, const int* in_sizes, int n_in,
                              void* d_out, int out_size, void* d_ws, size_t ws_size,
                              hipStream_t stream) {
    const float* hidden = (const float*)d_in[0];
    const float* w1     = (const float*)d_in[1];
    const float* w2     = (const float*)d_in[2];
    const float* gating = (const float*)d_in[3];
    float* out = (float*)d_out;

    const size_t N0 = (size_t)T_TOK * H_DIM;             // hidden elems
    const size_t N1 = (size_t)E_NUM * 2 * I_DIM * H_DIM; // w1 elems
    const size_t N2 = (size_t)E_NUM * H_DIM * I_DIM;     // w2 elems

    char* ws = (char*)d_ws;
    size_t off = 0;
    auto alloc = [&](size_t bytes) -> void* {
        void* p = ws + off;
        off += (bytes + 255) & ~(size_t)255;
        return p;
    };
    // order matters: act must not be last (gemm2 A-staging over-reads <=260KB)
    float*  ybuf  = (float*)alloc((size_t)2 * P_MAX * H_DIM * sizeof(float));     // 33.6 MB (2 slices)
    bf16_t* act   = (bf16_t*)alloc((size_t)P_MAX * I_DIM * sizeof(bf16_t));       // 16.8 MB
    bf16_t* hbf   = (bf16_t*)alloc(N0 * sizeof(bf16_t));                          //  4.2 MB
    bf16_t* w1bf  = (bf16_t*)alloc(N1 * sizeof(bf16_t));                          // 67.1 MB
    bf16_t* w2bf  = (bf16_t*)alloc(N2 * sizeof(bf16_t));                          // 33.6 MB
    int*    expert_id  = (int*)alloc(P_MAX * sizeof(int));
    float*  wt         = (float*)alloc(P_MAX * sizeof(float));
    int*    pair_token = (int*)alloc(P_MAX * sizeof(int));
    int*    pair_dst   = (int*)alloc(P_MAX * sizeof(int));
    float*  pair_wt    = (float*)alloc(P_MAX * sizeof(float));
    int*    counts     = (int*)alloc(E_NUM * sizeof(int));
    int*    offsets    = (int*)alloc((E_NUM + 1) * sizeof(int));
    int*    cursor     = (int*)alloc(E_NUM * sizeof(int));
    int*    n_slots    = (int*)alloc(sizeof(int));
    int*    tile_e     = (int*)alloc(MAX_SLOTS * sizeof(int));
    int*    tile_m0    = (int*)alloc(MAX_SLOTS * sizeof(int));

    init_kernel<<<1, 64, 0, stream>>>(counts, cursor);
    router_kernel<<<(T_TOK + 255) / 256, 256, 0, stream>>>(gating, expert_id, wt, counts);
    scan_kernel<<<1, 1, 0, stream>>>(counts, offsets, tile_e, tile_m0, n_slots);
    scatter_kernel<<<(T_TOK + 255) / 256, 256, 0, stream>>>(expert_id, wt, offsets, cursor,
                                                            pair_token, pair_dst, pair_wt);
    convert_kernel<<<(int)(N0 / (256 * 16)), 256, 0, stream>>>(hidden, hbf);
    convert_kernel<<<(int)(N1 / (256 * 16)), 256, 0, stream>>>(w1, w1bf);
    convert_kernel<<<(int)(N2 / (256 * 16)), 256, 0, stream>>>(w2, w2bf);
    gemm1_kernel<<<768, 512, 0, stream>>>(
        hbf, w1bf, pair_token, offsets, tile_e, tile_m0, n_slots, act);
    gemm2_kernel<<<512, 512, 0, stream>>>(
        act, w2bf, offsets, tile_e, tile_m0, n_slots, pair_dst, pair_wt, ybuf);
    combine_kernel<<<(T_TOK * H_DIM / 4) / 256, 256, 0, stream>>>(ybuf, out);

    (void)in_sizes; (void)n_in; (void)out_size; (void)ws_size;
}

// Round 13
// 211.814 us; speedup vs baseline: 1.9549x; 1.9549x over previous
//
#include <hip/hip_runtime.h>
#include <hip/hip_bf16.h>
#include <math.h>

// Problem constants (fixed by the reference file)
#define T_TOK 2048
#define H_DIM 1024
#define I_DIM 2048
#define E_NUM 8
#define TOPK  2
#define P_MAX (T_TOK * TOPK)   // 4096 (token, k) pairs
#define MAX_SLOTS 40           // max 128-row slots: 4096/128 + 8

typedef __bf16 bf16_t;
typedef __attribute__((ext_vector_type(8))) __bf16 bf16x8;
typedef __attribute__((ext_vector_type(4))) float  f32x4;

// global_load_lds: per-lane GLOBAL address, wave-uniform LDS base; lane n
// writes lds_base + n*16 bytes (m104/m108).
#define GLOAD_LDS16(gptr, lptr)                                                   \
    __builtin_amdgcn_global_load_lds(                                             \
        (const __attribute__((address_space(1))) void*)(gptr),                    \
        (__attribute__((address_space(3))) void*)(lptr), 16, 0, 0)

__device__ inline f32x4 zero4() {
    f32x4 z; z[0] = 0.f; z[1] = 0.f; z[2] = 0.f; z[3] = 0.f; return z;
}

__device__ inline bf16x8 cvt8(f32x4 a, f32x4 b) {
    bf16x8 o;
    o[0] = (bf16_t)a[0]; o[1] = (bf16_t)a[1]; o[2] = (bf16_t)a[2]; o[3] = (bf16_t)a[3];
    o[4] = (bf16_t)b[0]; o[5] = (bf16_t)b[1]; o[6] = (bf16_t)b[2]; o[7] = (bf16_t)b[3];
    return o;
}

// ---------------------------------------------------------------- init
__global__ void init_kernel(int* counts, int* cursor) {
    int i = threadIdx.x;
    if (i < E_NUM) { counts[i] = 0; cursor[i] = 0; }
}

// ---------------------------------------------------------------- router
__global__ void router_kernel(const float* __restrict__ gating,
                              int* __restrict__ expert_id,
                              float* __restrict__ wt,
                              int* __restrict__ counts) {
    int t = blockIdx.x * blockDim.x + threadIdx.x;
    if (t >= T_TOK) return;
    float l[E_NUM];
    float m = -1e30f;
    #pragma unroll
    for (int e = 0; e < E_NUM; e++) { l[e] = gating[t * E_NUM + e]; m = fmaxf(m, l[e]); }
    float p[E_NUM];
    #pragma unroll
    for (int e = 0; e < E_NUM; e++) p[e] = __expf(l[e] - m);
    int i0 = 0; float p0 = p[0];
    #pragma unroll
    for (int e = 1; e < E_NUM; e++) if (p[e] > p0) { p0 = p[e]; i0 = e; }
    int i1 = -1; float p1 = -1.f;
    #pragma unroll
    for (int e = 0; e < E_NUM; e++) if (e != i0 && p[e] > p1) { p1 = p[e]; i1 = e; }
    float inv = 1.f / (p0 + p1);
    expert_id[t * 2 + 0] = i0; wt[t * 2 + 0] = p0 * inv;
    expert_id[t * 2 + 1] = i1; wt[t * 2 + 1] = p1 * inv;
    atomicAdd(&counts[i0], 1);
    atomicAdd(&counts[i1], 1);
}

// ---------------------------------------------------------------- scan + tile map
__global__ void scan_kernel(const int* __restrict__ counts,
                            int* __restrict__ offsets,
                            int* __restrict__ tile_e, int* __restrict__ tile_m0,
                            int* __restrict__ n_slots) {
    if (threadIdx.x != 0 || blockIdx.x != 0) return;
    int off = 0;
    for (int e = 0; e < E_NUM; e++) { offsets[e] = off; off += counts[e]; }
    offsets[E_NUM] = off;
    int s = 0;
    for (int e = 0; e < E_NUM; e++)
        for (int m0 = offsets[e]; m0 < offsets[e + 1]; m0 += 128) {
            tile_e[s] = e; tile_m0[s] = m0; s++;
        }
    *n_slots = s;
}

// ---------------------------------------------------------------- scatter
__global__ void scatter_kernel(const int* __restrict__ expert_id,
                               const float* __restrict__ wt,
                               const int* __restrict__ offsets,
                               int* __restrict__ cursor,
                               int* __restrict__ pair_token,
                               int* __restrict__ pair_dst,
                               float* __restrict__ pair_wt) {
    int t = blockIdx.x * blockDim.x + threadIdx.x;
    if (t >= T_TOK) return;
    #pragma unroll
    for (int k = 0; k < TOPK; k++) {
        int e = expert_id[t * 2 + k];
        int p = offsets[e] + atomicAdd(&cursor[e], 1);
        pair_token[p] = t;
        pair_dst[p]   = t * 2 + k;
        pair_wt[p]    = wt[t * 2 + k];
    }
}

// ---------------------------------------------------------------- f32 -> bf16 convert
__global__ void convert_kernel(const float* __restrict__ src,
                               bf16_t* __restrict__ dst) {
    size_t base = ((size_t)blockIdx.x * blockDim.x + threadIdx.x) * 16;
    f32x4 v0 = *(const f32x4*)(src + base);
    f32x4 v1 = *(const f32x4*)(src + base + 4);
    f32x4 v2 = *(const f32x4*)(src + base + 8);
    f32x4 v3 = *(const f32x4*)(src + base + 12);
    *(bf16x8*)(dst + base)     = cvt8(v0, v1);
    *(bf16x8*)(dst + base + 8) = cvt8(v2, v3);
}

// ---------------------------------------------------------------- GEMM1 + SwiGLU
// R8 counted-vmcnt pipeline (T3/T4), engine byte-identical to R8.
// Quantization fix ONLY: grid 768 (= 3 blocks/CU, LDS-bound 160/48) so all
// ~528 items are resident in ONE generation (R8's grid 512 < nit 528 made
// ~16 blocks run 2 sequential items -> wall = 2 x T_item).
// launch_bounds stays (512,4): R12's (512,6) forced VGPR 60->40 and spilled
// the accumulator to scratch (WRITE_SIZE 516 MB, 277 us).
__global__ __launch_bounds__(512, 4)
void gemm1_kernel(const bf16_t* __restrict__ hbf,
                  const bf16_t* __restrict__ w1bf,
                  const int* __restrict__ pair_token,
                  const int* __restrict__ offsets,
                  const int* __restrict__ tile_e,
                  const int* __restrict__ tile_m0,
                  const int* __restrict__ n_slots,
                  bf16_t* __restrict__ act) {
    __shared__ __align__(16) bf16_t sA[2][128][32];  // 16 KB
    __shared__ __align__(16) bf16_t sB[2][256][32];  // 32 KB

    int tid = threadIdx.x;
    int lane = tid & 63, w = tid >> 6;     // 8 waves
    int wm = w >> 2, wn = w & 3;           // 2M x 4N
    int l15 = lane & 15, lg = lane >> 4;
    int sr = lane >> 2, sg = lane & 3;     // staging sub-row / granule
    int gcol = (sg ^ (sr & 3)) * 8;        // inverse-swizzled SOURCE granule
    int rg   = (lg ^ (l15 & 3)) * 8;       // swizzled READ granule

    int nit = *n_slots * 16;
    for (int it = blockIdx.x; it < nit; it += gridDim.x) {
        int slot = it >> 4;
        int c0   = (it & 15) << 7;         // act cols [c0, c0+128)
        int e    = tile_e[slot];
        int m0   = tile_m0[slot];
        int mend = offsets[e + 1];
        const bf16_t* w1e = w1bf + (size_t)e * (2 * I_DIM) * H_DIM;

        // staging addresses (k0 added in loop)
        int parow = m0 + w * 16 + sr;
        int tok = (parow < mend) ? pair_token[parow] : 0;  // dummy, masked later
        const bf16_t* gA0 = hbf + (size_t)tok * H_DIM + gcol;
        int br0 = w * 32 + sr, br1 = br0 + 16;
        int wr0 = (br0 < 128) ? (c0 + br0) : (I_DIM + c0 + br0 - 128);
        int wr1 = (br1 < 128) ? (c0 + br1) : (I_DIM + c0 + br1 - 128);
        const bf16_t* gB0 = w1e + (size_t)wr0 * H_DIM + gcol;
        const bf16_t* gB1 = w1e + (size_t)wr1 * H_DIM + gcol;

        f32x4 acc[4][4];  // j=0,1 gate; j=2,3 up
        #pragma unroll
        for (int i = 0; i < 4; i++)
            #pragma unroll
            for (int j = 0; j < 4; j++) acc[i][j] = zero4();

        // prologue: stage K-step 0 into buf 0
        GLOAD_LDS16(gA0, &sA[0][w * 16][0]);
        GLOAD_LDS16(gB0, &sB[0][w * 32][0]);
        GLOAD_LDS16(gB1, &sB[0][w * 32 + 16][0]);

        for (int t = 0; t < 32; t++) {
            int cur = t & 1;
            if (t < 31) {
                int k0 = (t + 1) * 32;
                GLOAD_LDS16(gA0 + k0, &sA[cur ^ 1][w * 16][0]);
                GLOAD_LDS16(gB0 + k0, &sB[cur ^ 1][w * 32][0]);
                GLOAD_LDS16(gB1 + k0, &sB[cur ^ 1][w * 32 + 16][0]);
                asm volatile("s_waitcnt vmcnt(3)" ::: "memory");
            } else {
                asm volatile("s_waitcnt vmcnt(0)" ::: "memory");
            }
            __builtin_amdgcn_s_barrier();   // all waves' cur-tile loads landed

            bf16x8 a[4], bg[2], bu[2];
            #pragma unroll
            for (int i = 0; i < 4; i++)
                a[i] = *(const bf16x8*)&sA[cur][wm * 64 + i * 16 + l15][rg];
            #pragma unroll
            for (int j = 0; j < 2; j++) {
                bg[j] = *(const bf16x8*)&sB[cur][wn * 32 + j * 16 + l15][rg];
                bu[j] = *(const bf16x8*)&sB[cur][128 + wn * 32 + j * 16 + l15][rg];
            }
            #pragma unroll
            for (int i = 0; i < 4; i++)
                #pragma unroll
                for (int j = 0; j < 2; j++) {
                    acc[i][j]     = __builtin_amdgcn_mfma_f32_16x16x32_bf16(a[i], bg[j], acc[i][j], 0, 0, 0);
                    acc[i][2 + j] = __builtin_amdgcn_mfma_f32_16x16x32_bf16(a[i], bu[j], acc[i][2 + j], 0, 0, 0);
                }
            __builtin_amdgcn_sched_barrier(0);  // keep MFMAs before barrier
            __builtin_amdgcn_s_barrier();       // cur reusable for next stage
        }

        // epilogue: act = silu(gate) * up
        #pragma unroll
        for (int i = 0; i < 4; i++) {
            #pragma unroll
            for (int rr = 0; rr < 4; rr++) {
                int m = m0 + wm * 64 + i * 16 + lg * 4 + rr;
                if (m < mend) {
                    #pragma unroll
                    for (int j = 0; j < 2; j++) {
                        float gv = acc[i][j][rr];
                        float uv = acc[i][2 + j][rr];
                        float sv = gv / (1.f + __expf(-gv));
                        act[(size_t)m * I_DIM + c0 + wn * 32 + j * 16 + l15] = (bf16_t)(sv * uv);
                    }
                }
            }
        }
    }
}

// ---------------------------------------------------------------- GEMM2 (+ scale, k-split)
// R8 engine unchanged. nit = n_slots*8 (~264) <= 512 block slots at
// 2 blocks/CU -> already fully resident; grid 512 covers worst case.
__global__ __launch_bounds__(512, 4)
void gemm2_kernel(const bf16_t* __restrict__ act,
                  const bf16_t* __restrict__ w2bf,
                  const int* __restrict__ offsets,
                  const int* __restrict__ tile_e,
                  const int* __restrict__ tile_m0,
                  const int* __restrict__ n_slots,
                  const int* __restrict__ pair_dst,
                  const float* __restrict__ pair_wt,
                  float* __restrict__ ybuf) {
    __shared__ __align__(16) bf16_t sA[2][128][32];
    __shared__ __align__(16) bf16_t sB[2][256][32];

    int tid = threadIdx.x;
    int lane = tid & 63, w = tid >> 6;
    int wm = w >> 2, wn = w & 3;
    int l15 = lane & 15, lg = lane >> 4;
    int sr = lane >> 2, sg = lane & 3;
    int gcol = (sg ^ (sr & 3)) * 8;
    int rg   = (lg ^ (l15 & 3)) * 8;

    int nit = *n_slots * 8;    // 4 n0-groups x 2 kz
    for (int it = blockIdx.x; it < nit; it += gridDim.x) {
        int slot = it >> 3;
        int n0   = ((it >> 1) & 3) << 8;   // out cols [n0, n0+256)
        int kz   = it & 1;
        int kb   = kz << 10;               // k-slice base (1024)
        int e    = tile_e[slot];
        int m0   = tile_m0[slot];
        int mend = offsets[e + 1];
        const bf16_t* w2e = w2bf + (size_t)e * H_DIM * I_DIM;

        // rows >= mend read neighbor arena data (masked at epilogue)
        const bf16_t* gA0 = act + (size_t)(m0 + w * 16 + sr) * I_DIM + kb + gcol;
        const bf16_t* gB0 = w2e + (size_t)(n0 + w * 32 + sr) * I_DIM + kb + gcol;
        const bf16_t* gB1 = w2e + (size_t)(n0 + w * 32 + 16 + sr) * I_DIM + kb + gcol;

        f32x4 acc[4][4];
        #pragma unroll
        for (int i = 0; i < 4; i++)
            #pragma unroll
            for (int j = 0; j < 4; j++) acc[i][j] = zero4();

        GLOAD_LDS16(gA0, &sA[0][w * 16][0]);
        GLOAD_LDS16(gB0, &sB[0][w * 32][0]);
        GLOAD_LDS16(gB1, &sB[0][w * 32 + 16][0]);

        for (int t = 0; t < 32; t++) {
            int cur = t & 1;
            if (t < 31) {
                int k0 = (t + 1) * 32;
                GLOAD_LDS16(gA0 + k0, &sA[cur ^ 1][w * 16][0]);
                GLOAD_LDS16(gB0 + k0, &sB[cur ^ 1][w * 32][0]);
                GLOAD_LDS16(gB1 + k0, &sB[cur ^ 1][w * 32 + 16][0]);
                asm volatile("s_waitcnt vmcnt(3)" ::: "memory");
            } else {
                asm volatile("s_waitcnt vmcnt(0)" ::: "memory");
            }
            __builtin_amdgcn_s_barrier();

            bf16x8 a[4], b[4];
            #pragma unroll
            for (int i = 0; i < 4; i++)
                a[i] = *(const bf16x8*)&sA[cur][wm * 64 + i * 16 + l15][rg];
            #pragma unroll
            for (int j = 0; j < 4; j++)
                b[j] = *(const bf16x8*)&sB[cur][wn * 64 + j * 16 + l15][rg];
            #pragma unroll
            for (int i = 0; i < 4; i++)
                #pragma unroll
                for (int j = 0; j < 4; j++)
                    acc[i][j] = __builtin_amdgcn_mfma_f32_16x16x32_bf16(a[i], b[j], acc[i][j], 0, 0, 0);
            __builtin_amdgcn_sched_barrier(0);
            __builtin_amdgcn_s_barrier();
        }

        float* ybufz = ybuf + (size_t)kz * P_MAX * H_DIM;
        #pragma unroll
        for (int i = 0; i < 4; i++) {
            #pragma unroll
            for (int rr = 0; rr < 4; rr++) {
                int m = m0 + wm * 64 + i * 16 + lg * 4 + rr;
                if (m < mend) {
                    int   dst = pair_dst[m];
                    float wv  = pair_wt[m];
                    #pragma unroll
                    for (int j = 0; j < 4; j++)
                        ybufz[(size_t)dst * H_DIM + n0 + wn * 64 + j * 16 + l15] = acc[i][j][rr] * wv;
                }
            }
        }
    }
}

// ---------------------------------------------------------------- combine
__global__ void combine_kernel(const float* __restrict__ ybuf,
                               float* __restrict__ out) {
    int idx = blockIdx.x * 256 + threadIdx.x;   // one float4 each
    int t = idx >> 8;                           // 256 float4 per token row
    int h = idx & 255;
    const size_t SL = (size_t)P_MAX * H_DIM;
    const f32x4* y00 = (const f32x4*)(ybuf + (size_t)(t * 2)     * H_DIM) + h;
    const f32x4* y01 = (const f32x4*)(ybuf + (size_t)(t * 2 + 1) * H_DIM) + h;
    const f32x4* y10 = (const f32x4*)(ybuf + SL + (size_t)(t * 2)     * H_DIM) + h;
    const f32x4* y11 = (const f32x4*)(ybuf + SL + (size_t)(t * 2 + 1) * H_DIM) + h;
    f32x4 s = (*y00 + *y10) + (*y01 + *y11);
    ((f32x4*)out)[idx] = s;
}

// ---------------------------------------------------------------- launch
extern "C" void kernel_launch(void* const* d_in, const int* in_sizes, int n_in,
                              void* d_out, int out_size, void* d_ws, size_t ws_size,
                              hipStream_t stream) {
    const float* hidden = (const float*)d_in[0];
    const float* w1     = (const float*)d_in[1];
    const float* w2     = (const float*)d_in[2];
    const float* gating = (const float*)d_in[3];
    float* out = (float*)d_out;

    const size_t N0 = (size_t)T_TOK * H_DIM;             // hidden elems
    const size_t N1 = (size_t)E_NUM * 2 * I_DIM * H_DIM; // w1 elems
    const size_t N2 = (size_t)E_NUM * H_DIM * I_DIM;     // w2 elems

    char* ws = (char*)d_ws;
    size_t off = 0;
    auto alloc = [&](size_t bytes) -> void* {
        void* p = ws + off;
        off += (bytes + 255) & ~(size_t)255;
        return p;
    };
    // order matters: act must not be last (gemm2 A-staging over-reads <=260KB)
    float*  ybuf  = (float*)alloc((size_t)2 * P_MAX * H_DIM * sizeof(float));     // 33.6 MB (2 slices)
    bf16_t* act   = (bf16_t*)alloc((size_t)P_MAX * I_DIM * sizeof(bf16_t));       // 16.8 MB
    bf16_t* hbf   = (bf16_t*)alloc(N0 * sizeof(bf16_t));                          //  4.2 MB
    bf16_t* w1bf  = (bf16_t*)alloc(N1 * sizeof(bf16_t));                          // 67.1 MB
    bf16_t* w2bf  = (bf16_t*)alloc(N2 * sizeof(bf16_t));                          // 33.6 MB
    int*    expert_id  = (int*)alloc(P_MAX * sizeof(int));
    float*  wt         = (float*)alloc(P_MAX * sizeof(float));
    int*    pair_token = (int*)alloc(P_MAX * sizeof(int));
    int*    pair_dst   = (int*)alloc(P_MAX * sizeof(int));
    float*  pair_wt    = (float*)alloc(P_MAX * sizeof(float));
    int*    counts     = (int*)alloc(E_NUM * sizeof(int));
    int*    offsets    = (int*)alloc((E_NUM + 1) * sizeof(int));
    int*    cursor     = (int*)alloc(E_NUM * sizeof(int));
    int*    n_slots    = (int*)alloc(sizeof(int));
    int*    tile_e     = (int*)alloc(MAX_SLOTS * sizeof(int));
    int*    tile_m0    = (int*)alloc(MAX_SLOTS * sizeof(int));

    init_kernel<<<1, 64, 0, stream>>>(counts, cursor);
    router_kernel<<<(T_TOK + 255) / 256, 256, 0, stream>>>(gating, expert_id, wt, counts);
    scan_kernel<<<1, 1, 0, stream>>>(counts, offsets, tile_e, tile_m0, n_slots);
    scatter_kernel<<<(T_TOK + 255) / 256, 256, 0, stream>>>(expert_id, wt, offsets, cursor,
                                                            pair_token, pair_dst, pair_wt);
    convert_kernel<<<(int)(N0 / (256 * 16)), 256, 0, stream>>>(hidden, hbf);
    convert_kernel<<<(int)(N1 / (256 * 16)), 256, 0, stream>>>(w1, w1bf);
    convert_kernel<<<(int)(N2 / (256 * 16)), 256, 0, stream>>>(w2, w2bf);
    gemm1_kernel<<<768, 512, 0, stream>>>(
        hbf, w1bf, pair_token, offsets, tile_e, tile_m0, n_slots, act);
    gemm2_kernel<<<512, 512, 0, stream>>>(
        act, w2bf, offsets, tile_e, tile_m0, n_slots, pair_dst, pair_wt, ybuf);
    combine_kernel<<<(T_TOK * H_DIM / 4) / 256, 256, 0, stream>>>(ybuf, out);

    (void)in_sizes; (void)n_in; (void)out_size; (void)ws_size;
}

// Round 14
// 210.588 us; speedup vs baseline: 1.9663x; 1.0058x over previous
//
#include <hip/hip_runtime.h>
#include <hip/hip_bf16.h>
#include <math.h>

// Problem constants (fixed by the reference file)
#define T_TOK 2048
#define H_DIM 1024
#define I_DIM 2048
#define E_NUM 8
#define TOPK  2
#define P_MAX (T_TOK * TOPK)   // 4096 (token, k) pairs
#define MAX_SLOTS 40           // max 128-row slots: 4096/128 + 8

typedef __bf16 bf16_t;
typedef __attribute__((ext_vector_type(8))) __bf16 bf16x8;
typedef __attribute__((ext_vector_type(4))) float  f32x4;

// global_load_lds: per-lane GLOBAL address, wave-uniform LDS base; lane n
// writes lds_base + n*16 bytes (m104/m108).
#define GLOAD_LDS16(gptr, lptr)                                                   \
    __builtin_amdgcn_global_load_lds(                                             \
        (const __attribute__((address_space(1))) void*)(gptr),                    \
        (__attribute__((address_space(3))) void*)(lptr), 16, 0, 0)

// compiler-only ordering fence (no instruction emitted): pins issue order of
// surrounding memory ops so vmcnt(N) arithmetic is exact.
#define ORDER_FENCE() asm volatile("" ::: "memory")

__device__ inline f32x4 zero4() {
    f32x4 z; z[0] = 0.f; z[1] = 0.f; z[2] = 0.f; z[3] = 0.f; return z;
}

__device__ inline bf16x8 cvt8(f32x4 a, f32x4 b) {
    bf16x8 o;
    o[0] = (bf16_t)a[0]; o[1] = (bf16_t)a[1]; o[2] = (bf16_t)a[2]; o[3] = (bf16_t)a[3];
    o[4] = (bf16_t)b[0]; o[5] = (bf16_t)b[1]; o[6] = (bf16_t)b[2]; o[7] = (bf16_t)b[3];
    return o;
}

// ---------------------------------------------------------------- init
__global__ void init_kernel(int* counts, int* cursor) {
    int i = threadIdx.x;
    if (i < E_NUM) { counts[i] = 0; cursor[i] = 0; }
}

// ---------------------------------------------------------------- router
__global__ void router_kernel(const float* __restrict__ gating,
                              int* __restrict__ expert_id,
                              float* __restrict__ wt,
                              int* __restrict__ counts) {
    int t = blockIdx.x * blockDim.x + threadIdx.x;
    if (t >= T_TOK) return;
    float l[E_NUM];
    float m = -1e30f;
    #pragma unroll
    for (int e = 0; e < E_NUM; e++) { l[e] = gating[t * E_NUM + e]; m = fmaxf(m, l[e]); }
    float p[E_NUM];
    #pragma unroll
    for (int e = 0; e < E_NUM; e++) p[e] = __expf(l[e] - m);
    int i0 = 0; float p0 = p[0];
    #pragma unroll
    for (int e = 1; e < E_NUM; e++) if (p[e] > p0) { p0 = p[e]; i0 = e; }
    int i1 = -1; float p1 = -1.f;
    #pragma unroll
    for (int e = 0; e < E_NUM; e++) if (e != i0 && p[e] > p1) { p1 = p[e]; i1 = e; }
    float inv = 1.f / (p0 + p1);
    expert_id[t * 2 + 0] = i0; wt[t * 2 + 0] = p0 * inv;
    expert_id[t * 2 + 1] = i1; wt[t * 2 + 1] = p1 * inv;
    atomicAdd(&counts[i0], 1);
    atomicAdd(&counts[i1], 1);
}

// ---------------------------------------------------------------- scan + tile map
__global__ void scan_kernel(const int* __restrict__ counts,
                            int* __restrict__ offsets,
                            int* __restrict__ tile_e, int* __restrict__ tile_m0,
                            int* __restrict__ n_slots) {
    if (threadIdx.x != 0 || blockIdx.x != 0) return;
    int off = 0;
    for (int e = 0; e < E_NUM; e++) { offsets[e] = off; off += counts[e]; }
    offsets[E_NUM] = off;
    int s = 0;
    for (int e = 0; e < E_NUM; e++)
        for (int m0 = offsets[e]; m0 < offsets[e + 1]; m0 += 128) {
            tile_e[s] = e; tile_m0[s] = m0; s++;
        }
    *n_slots = s;
}

// ---------------------------------------------------------------- scatter
__global__ void scatter_kernel(const int* __restrict__ expert_id,
                               const float* __restrict__ wt,
                               const int* __restrict__ offsets,
                               int* __restrict__ cursor,
                               int* __restrict__ pair_token,
                               int* __restrict__ pair_dst,
                               float* __restrict__ pair_wt) {
    int t = blockIdx.x * blockDim.x + threadIdx.x;
    if (t >= T_TOK) return;
    #pragma unroll
    for (int k = 0; k < TOPK; k++) {
        int e = expert_id[t * 2 + k];
        int p = offsets[e] + atomicAdd(&cursor[e], 1);
        pair_token[p] = t;
        pair_dst[p]   = t * 2 + k;
        pair_wt[p]    = wt[t * 2 + k];
    }
}

// ---------------------------------------------------------------- f32 -> bf16 convert (hidden only)
__global__ void convert_kernel(const float* __restrict__ src,
                               bf16_t* __restrict__ dst) {
    size_t base = ((size_t)blockIdx.x * blockDim.x + threadIdx.x) * 16;
    f32x4 v0 = *(const f32x4*)(src + base);
    f32x4 v1 = *(const f32x4*)(src + base + 4);
    f32x4 v2 = *(const f32x4*)(src + base + 8);
    f32x4 v3 = *(const f32x4*)(src + base + 12);
    *(bf16x8*)(dst + base)     = cvt8(v0, v1);
    *(bf16x8*)(dst + base + 8) = cvt8(v2, v3);
}

// ---------------------------------------------------------------- GEMM1 + SwiGLU
// R8 counted-vmcnt engine; w1 conversion FUSED into B-staging (kills the
// 48us weight-convert pass). Per K-step per thread: stage one (row, half)
// of next tile's B = 4x dwordx4 f32 loads (64B contiguous/lane), then after
// MFMA: vmcnt(1) -> cvt8 x2 -> 2x ds_write_b128 (write-side XOR swizzle,
// same algebra as read side). A stays global_load_lds from bf16 hbf.
// vmcnt choreography per iter: issue B(t+1)x4 then A(t+1)glds (order pinned
// by ORDER_FENCE); vmcnt(5) = A(t) landed; after MFMA vmcnt(1) = B regs
// ready (A(t+1) still in flight); lgkmcnt(0) before barrier-2 publishes
// the ds_writes.
__global__ __launch_bounds__(512, 4)
void gemm1_kernel(const bf16_t* __restrict__ hbf,
                  const float* __restrict__ w1,
                  const int* __restrict__ pair_token,
                  const int* __restrict__ offsets,
                  const int* __restrict__ tile_e,
                  const int* __restrict__ tile_m0,
                  const int* __restrict__ n_slots,
                  bf16_t* __restrict__ act) {
    __shared__ __align__(16) bf16_t sA[2][128][32];  // 16 KB
    __shared__ __align__(16) bf16_t sB[2][256][32];  // 32 KB

    int tid = threadIdx.x;
    int lane = tid & 63, w = tid >> 6;     // 8 waves
    int wm = w >> 2, wn = w & 3;           // 2M x 4N
    int l15 = lane & 15, lg = lane >> 4;
    int sr = lane >> 2, sg = lane & 3;     // A staging sub-row / granule
    int gcol = (sg ^ (sr & 3)) * 8;        // A: inverse-swizzled SOURCE granule
    int rg   = (lg ^ (l15 & 3)) * 8;       // swizzled READ granule

    // B staging map: thread -> (row, half); 256 rows x 2 halves of 16 f32
    int brow = tid >> 1, bhalf = tid & 1;
    int bg0 = ((bhalf * 2)     ^ (brow & 3)) * 8;   // swizzled write granules
    int bg1 = ((bhalf * 2 + 1) ^ (brow & 3)) * 8;

    int nit = *n_slots * 16;
    for (int it = blockIdx.x; it < nit; it += gridDim.x) {
        int slot = it >> 4;
        int c0   = (it & 15) << 7;         // act cols [c0, c0+128)
        int e    = tile_e[slot];
        int m0   = tile_m0[slot];
        int mend = offsets[e + 1];
        const float* w1e = w1 + (size_t)e * (2 * I_DIM) * H_DIM;

        // A staging address (k0 added in loop)
        int parow = m0 + w * 16 + sr;
        int tok = (parow < mend) ? pair_token[parow] : 0;  // dummy, masked later
        const bf16_t* gA0 = hbf + (size_t)tok * H_DIM + gcol;
        // B staging address (f32 weights, k0 added in loop)
        int w1row = (brow < 128) ? (c0 + brow) : (I_DIM + c0 + brow - 128);
        const float* gBf = w1e + (size_t)w1row * H_DIM + bhalf * 16;

        f32x4 acc[4][4];  // j=0,1 gate; j=2,3 up
        #pragma unroll
        for (int i = 0; i < 4; i++)
            #pragma unroll
            for (int j = 0; j < 4; j++) acc[i][j] = zero4();

        // prologue: stage K-step 0 into buf 0
        f32x4 bq0 = *(const f32x4*)(gBf);
        f32x4 bq1 = *(const f32x4*)(gBf + 4);
        f32x4 bq2 = *(const f32x4*)(gBf + 8);
        f32x4 bq3 = *(const f32x4*)(gBf + 12);
        ORDER_FENCE();
        GLOAD_LDS16(gA0, &sA[0][w * 16][0]);
        asm volatile("s_waitcnt vmcnt(1)" ::: "memory");   // B(0) regs ready
        *(bf16x8*)&sB[0][brow][bg0] = cvt8(bq0, bq1);
        *(bf16x8*)&sB[0][brow][bg1] = cvt8(bq2, bq3);
        asm volatile("s_waitcnt lgkmcnt(0)" ::: "memory"); // writes done pre-barrier

        for (int t = 0; t < 32; t++) {
            int cur = t & 1;
            if (t < 31) {
                int k0 = (t + 1) * 32;
                bq0 = *(const f32x4*)(gBf + k0);
                bq1 = *(const f32x4*)(gBf + k0 + 4);
                bq2 = *(const f32x4*)(gBf + k0 + 8);
                bq3 = *(const f32x4*)(gBf + k0 + 12);
                ORDER_FENCE();
                GLOAD_LDS16(gA0 + k0, &sA[cur ^ 1][w * 16][0]);
                asm volatile("s_waitcnt vmcnt(5)" ::: "memory");  // A(t) landed
            } else {
                asm volatile("s_waitcnt vmcnt(0)" ::: "memory");
            }
            __builtin_amdgcn_s_barrier();   // cur tile (A glds + B writes) visible

            bf16x8 a[4], bg[2], bu[2];
            #pragma unroll
            for (int i = 0; i < 4; i++)
                a[i] = *(const bf16x8*)&sA[cur][wm * 64 + i * 16 + l15][rg];
            #pragma unroll
            for (int j = 0; j < 2; j++) {
                bg[j] = *(const bf16x8*)&sB[cur][wn * 32 + j * 16 + l15][rg];
                bu[j] = *(const bf16x8*)&sB[cur][128 + wn * 32 + j * 16 + l15][rg];
            }
            #pragma unroll
            for (int i = 0; i < 4; i++)
                #pragma unroll
                for (int j = 0; j < 2; j++) {
                    acc[i][j]     = __builtin_amdgcn_mfma_f32_16x16x32_bf16(a[i], bg[j], acc[i][j], 0, 0, 0);
                    acc[i][2 + j] = __builtin_amdgcn_mfma_f32_16x16x32_bf16(a[i], bu[j], acc[i][2 + j], 0, 0, 0);
                }
            __builtin_amdgcn_sched_barrier(0);  // keep MFMAs before the waits below
            if (t < 31) {
                asm volatile("s_waitcnt vmcnt(1)" ::: "memory");  // B(t+1) regs ready
                *(bf16x8*)&sB[cur ^ 1][brow][bg0] = cvt8(bq0, bq1);
                *(bf16x8*)&sB[cur ^ 1][brow][bg1] = cvt8(bq2, bq3);
                asm volatile("s_waitcnt lgkmcnt(0)" ::: "memory");
            }
            __builtin_amdgcn_sched_barrier(0);
            __builtin_amdgcn_s_barrier();       // next tile published; cur reusable
        }

        // epilogue: act = silu(gate) * up
        #pragma unroll
        for (int i = 0; i < 4; i++) {
            #pragma unroll
            for (int rr = 0; rr < 4; rr++) {
                int m = m0 + wm * 64 + i * 16 + lg * 4 + rr;
                if (m < mend) {
                    #pragma unroll
                    for (int j = 0; j < 2; j++) {
                        float gv = acc[i][j][rr];
                        float uv = acc[i][2 + j][rr];
                        float sv = gv / (1.f + __expf(-gv));
                        act[(size_t)m * I_DIM + c0 + wn * 32 + j * 16 + l15] = (bf16_t)(sv * uv);
                    }
                }
            }
        }
    }
}

// ---------------------------------------------------------------- GEMM2 (+ scale, k-split)
// Same fused engine: A = act (bf16, gl_lds); B = w2 (f32, reg-staged cvt).
__global__ __launch_bounds__(512, 4)
void gemm2_kernel(const bf16_t* __restrict__ act,
                  const float* __restrict__ w2,
                  const int* __restrict__ offsets,
                  const int* __restrict__ tile_e,
                  const int* __restrict__ tile_m0,
                  const int* __restrict__ n_slots,
                  const int* __restrict__ pair_dst,
                  const float* __restrict__ pair_wt,
                  float* __restrict__ ybuf) {
    __shared__ __align__(16) bf16_t sA[2][128][32];
    __shared__ __align__(16) bf16_t sB[2][256][32];

    int tid = threadIdx.x;
    int lane = tid & 63, w = tid >> 6;
    int wm = w >> 2, wn = w & 3;
    int l15 = lane & 15, lg = lane >> 4;
    int sr = lane >> 2, sg = lane & 3;
    int gcol = (sg ^ (sr & 3)) * 8;
    int rg   = (lg ^ (l15 & 3)) * 8;

    int brow = tid >> 1, bhalf = tid & 1;
    int bg0 = ((bhalf * 2)     ^ (brow & 3)) * 8;
    int bg1 = ((bhalf * 2 + 1) ^ (brow & 3)) * 8;

    int nit = *n_slots * 8;    // 4 n0-groups x 2 kz
    for (int it = blockIdx.x; it < nit; it += gridDim.x) {
        int slot = it >> 3;
        int n0   = ((it >> 1) & 3) << 8;   // out cols [n0, n0+256)
        int kz   = it & 1;
        int kb   = kz << 10;               // k-slice base (1024)
        int e    = tile_e[slot];
        int m0   = tile_m0[slot];
        int mend = offsets[e + 1];
        const float* w2e = w2 + (size_t)e * H_DIM * I_DIM;

        // rows >= mend read neighbor arena data (masked at epilogue)
        const bf16_t* gA0 = act + (size_t)(m0 + w * 16 + sr) * I_DIM + kb + gcol;
        const float*  gBf = w2e + (size_t)(n0 + brow) * I_DIM + kb + bhalf * 16;

        f32x4 acc[4][4];
        #pragma unroll
        for (int i = 0; i < 4; i++)
            #pragma unroll
            for (int j = 0; j < 4; j++) acc[i][j] = zero4();

        f32x4 bq0 = *(const f32x4*)(gBf);
        f32x4 bq1 = *(const f32x4*)(gBf + 4);
        f32x4 bq2 = *(const f32x4*)(gBf + 8);
        f32x4 bq3 = *(const f32x4*)(gBf + 12);
        ORDER_FENCE();
        GLOAD_LDS16(gA0, &sA[0][w * 16][0]);
        asm volatile("s_waitcnt vmcnt(1)" ::: "memory");
        *(bf16x8*)&sB[0][brow][bg0] = cvt8(bq0, bq1);
        *(bf16x8*)&sB[0][brow][bg1] = cvt8(bq2, bq3);
        asm volatile("s_waitcnt lgkmcnt(0)" ::: "memory");

        for (int t = 0; t < 32; t++) {
            int cur = t & 1;
            if (t < 31) {
                int k0 = (t + 1) * 32;
                bq0 = *(const f32x4*)(gBf + k0);
                bq1 = *(const f32x4*)(gBf + k0 + 4);
                bq2 = *(const f32x4*)(gBf + k0 + 8);
                bq3 = *(const f32x4*)(gBf + k0 + 12);
                ORDER_FENCE();
                GLOAD_LDS16(gA0 + k0, &sA[cur ^ 1][w * 16][0]);
                asm volatile("s_waitcnt vmcnt(5)" ::: "memory");
            } else {
                asm volatile("s_waitcnt vmcnt(0)" ::: "memory");
            }
            __builtin_amdgcn_s_barrier();

            bf16x8 a[4], b[4];
            #pragma unroll
            for (int i = 0; i < 4; i++)
                a[i] = *(const bf16x8*)&sA[cur][wm * 64 + i * 16 + l15][rg];
            #pragma unroll
            for (int j = 0; j < 4; j++)
                b[j] = *(const bf16x8*)&sB[cur][wn * 64 + j * 16 + l15][rg];
            #pragma unroll
            for (int i = 0; i < 4; i++)
                #pragma unroll
                for (int j = 0; j < 4; j++)
                    acc[i][j] = __builtin_amdgcn_mfma_f32_16x16x32_bf16(a[i], b[j], acc[i][j], 0, 0, 0);
            __builtin_amdgcn_sched_barrier(0);
            if (t < 31) {
                asm volatile("s_waitcnt vmcnt(1)" ::: "memory");
                *(bf16x8*)&sB[cur ^ 1][brow][bg0] = cvt8(bq0, bq1);
                *(bf16x8*)&sB[cur ^ 1][brow][bg1] = cvt8(bq2, bq3);
                asm volatile("s_waitcnt lgkmcnt(0)" ::: "memory");
            }
            __builtin_amdgcn_sched_barrier(0);
            __builtin_amdgcn_s_barrier();
        }

        float* ybufz = ybuf + (size_t)kz * P_MAX * H_DIM;
        #pragma unroll
        for (int i = 0; i < 4; i++) {
            #pragma unroll
            for (int rr = 0; rr < 4; rr++) {
                int m = m0 + wm * 64 + i * 16 + lg * 4 + rr;
                if (m < mend) {
                    int   dst = pair_dst[m];
                    float wv  = pair_wt[m];
                    #pragma unroll
                    for (int j = 0; j < 4; j++)
                        ybufz[(size_t)dst * H_DIM + n0 + wn * 64 + j * 16 + l15] = acc[i][j][rr] * wv;
                }
            }
        }
    }
}

// ---------------------------------------------------------------- combine
__global__ void combine_kernel(const float* __restrict__ ybuf,
                               float* __restrict__ out) {
    int idx = blockIdx.x * 256 + threadIdx.x;   // one float4 each
    int t = idx >> 8;                           // 256 float4 per token row
    int h = idx & 255;
    const size_t SL = (size_t)P_MAX * H_DIM;
    const f32x4* y00 = (const f32x4*)(ybuf + (size_t)(t * 2)     * H_DIM) + h;
    const f32x4* y01 = (const f32x4*)(ybuf + (size_t)(t * 2 + 1) * H_DIM) + h;
    const f32x4* y10 = (const f32x4*)(ybuf + SL + (size_t)(t * 2)     * H_DIM) + h;
    const f32x4* y11 = (const f32x4*)(ybuf + SL + (size_t)(t * 2 + 1) * H_DIM) + h;
    f32x4 s = (*y00 + *y10) + (*y01 + *y11);
    ((f32x4*)out)[idx] = s;
}

// ---------------------------------------------------------------- launch
extern "C" void kernel_launch(void* const* d_in, const int* in_sizes, int n_in,
                              void* d_out, int out_size, void* d_ws, size_t ws_size,
                              hipStream_t stream) {
    const float* hidden = (const float*)d_in[0];
    const float* w1     = (const float*)d_in[1];
    const float* w2     = (const float*)d_in[2];
    const float* gating = (const float*)d_in[3];
    float* out = (float*)d_out;

    const size_t N0 = (size_t)T_TOK * H_DIM;             // hidden elems

    char* ws = (char*)d_ws;
    size_t off = 0;
    auto alloc = [&](size_t bytes) -> void* {
        void* p = ws + off;
        off += (bytes + 255) & ~(size_t)255;
        return p;
    };
    // order matters: act must not be last (gemm2 A-staging over-reads <=260KB)
    float*  ybuf  = (float*)alloc((size_t)2 * P_MAX * H_DIM * sizeof(float));     // 33.6 MB (2 slices)
    bf16_t* act   = (bf16_t*)alloc((size_t)P_MAX * I_DIM * sizeof(bf16_t));       // 16.8 MB
    bf16_t* hbf   = (bf16_t*)alloc(N0 * sizeof(bf16_t));                          //  4.2 MB
    int*    expert_id  = (int*)alloc(P_MAX * sizeof(int));
    float*  wt         = (float*)alloc(P_MAX * sizeof(float));
    int*    pair_token = (int*)alloc(P_MAX * sizeof(int));
    int*    pair_dst   = (int*)alloc(P_MAX * sizeof(int));
    float*  pair_wt    = (float*)alloc(P_MAX * sizeof(float));
    int*    counts     = (int*)alloc(E_NUM * sizeof(int));
    int*    offsets    = (int*)alloc((E_NUM + 1) * sizeof(int));
    int*    cursor     = (int*)alloc(E_NUM * sizeof(int));
    int*    n_slots    = (int*)alloc(sizeof(int));
    int*    tile_e     = (int*)alloc(MAX_SLOTS * sizeof(int));
    int*    tile_m0    = (int*)alloc(MAX_SLOTS * sizeof(int));

    init_kernel<<<1, 64, 0, stream>>>(counts, cursor);
    router_kernel<<<(T_TOK + 255) / 256, 256, 0, stream>>>(gating, expert_id, wt, counts);
    scan_kernel<<<1, 1, 0, stream>>>(counts, offsets, tile_e, tile_m0, n_slots);
    scatter_kernel<<<(T_TOK + 255) / 256, 256, 0, stream>>>(expert_id, wt, offsets, cursor,
                                                            pair_token, pair_dst, pair_wt);
    convert_kernel<<<(int)(N0 / (256 * 16)), 256, 0, stream>>>(hidden, hbf);
    gemm1_kernel<<<768, 512, 0, stream>>>(
        hbf, w1, pair_token, offsets, tile_e, tile_m0, n_slots, act);
    gemm2_kernel<<<512, 512, 0, stream>>>(
        act, w2, offsets, tile_e, tile_m0, n_slots, pair_dst, pair_wt, ybuf);
    combine_kernel<<<(T_TOK * H_DIM / 4) / 256, 256, 0, stream>>>(ybuf, out);

    (void)in_sizes; (void)n_in; (void)out_size; (void)ws_size;
}